// Round 16
// baseline (8607.851 us; speedup 1.0000x reference)
//
#include <hip/hip_runtime.h>

typedef _Float16 f16;
typedef _Float16 f16x8 __attribute__((ext_vector_type(8)));
typedef float f32x4 __attribute__((ext_vector_type(4)));
typedef unsigned long long u64;
typedef unsigned short u16;
typedef unsigned int u32;

#define NT 2048
#define ND 512
#define NH 512
#define NWG 16
#define SENTW 0xFFFFFFFFFFFFFFFFull
#define SENTH ((u16)0xFFFFu)

__device__ __forceinline__ float sigf(float x)  { return 1.0f / (1.0f + __expf(-x)); }
__device__ __forceinline__ float tanhf_(float x){ return 2.0f / (1.0f + __expf(-2.0f * x)) - 1.0f; }

// any halfword of x == 0xFFFF ? (h finite -> f16 pattern 0xFFFF (NaN) unreachable)
__device__ __forceinline__ bool has_sent(u64 x) {
  u64 a = x & (x >> 8); a &= (a >> 4); a &= (a >> 2); a &= (a >> 1);
  return (a & 0x0001000100010001ull) != 0ull;
}

__device__ __forceinline__ int frag_idx(int b, int k0) {
  return ((k0 >> 5) * 2 + (b >> 4)) * 64 + ((k0 & 31) >> 3) * 16 + (b & 15);
}

// XCD-local (L2-coherent) primitives: sc0 bypasses L1, served by the XCD's L2.
__device__ __forceinline__ void st_u16_sc0(u16* p, u32 v) {
  asm volatile("global_store_short %0, %1, off sc0" :: "v"(p), "v"(v) : "memory");
}

// FULL-slot sweep (R9/R12 proven-live): words tid + 256*i, one vmcnt(0).
// Liveness is a COLLECTIVE property: all waves sweep the full 32KB each round.
// Narrower variants (flags, selective words, quarters) starve — R10/R11/R15.
__device__ __forceinline__ void gather16_sc0(const u64* slot, u32 tid, u64* g) {
  const u32 voff = tid * 8u;
  asm volatile(
    "global_load_dwordx2 %0, %16, %17 sc0\n\t"
    "global_load_dwordx2 %1, %16, %17 offset:2048 sc0\n\t"
    "global_load_dwordx2 %2, %16, %18 sc0\n\t"
    "global_load_dwordx2 %3, %16, %18 offset:2048 sc0\n\t"
    "global_load_dwordx2 %4, %16, %19 sc0\n\t"
    "global_load_dwordx2 %5, %16, %19 offset:2048 sc0\n\t"
    "global_load_dwordx2 %6, %16, %20 sc0\n\t"
    "global_load_dwordx2 %7, %16, %20 offset:2048 sc0\n\t"
    "global_load_dwordx2 %8, %16, %21 sc0\n\t"
    "global_load_dwordx2 %9, %16, %21 offset:2048 sc0\n\t"
    "global_load_dwordx2 %10, %16, %22 sc0\n\t"
    "global_load_dwordx2 %11, %16, %22 offset:2048 sc0\n\t"
    "global_load_dwordx2 %12, %16, %23 sc0\n\t"
    "global_load_dwordx2 %13, %16, %23 offset:2048 sc0\n\t"
    "global_load_dwordx2 %14, %16, %24 sc0\n\t"
    "global_load_dwordx2 %15, %16, %24 offset:2048 sc0\n\t"
    "s_waitcnt vmcnt(0)"
    : "=&v"(g[0]), "=&v"(g[1]), "=&v"(g[2]), "=&v"(g[3]),
      "=&v"(g[4]), "=&v"(g[5]), "=&v"(g[6]), "=&v"(g[7]),
      "=&v"(g[8]), "=&v"(g[9]), "=&v"(g[10]), "=&v"(g[11]),
      "=&v"(g[12]), "=&v"(g[13]), "=&v"(g[14]), "=&v"(g[15])
    : "v"(voff),
      "s"(slot), "s"(slot + 512), "s"(slot + 1024), "s"(slot + 1536),
      "s"(slot + 2048), "s"(slot + 2560), "s"(slot + 3072), "s"(slot + 3584)
    : "memory");
}

// ---- init: hg slot0 = h_prev in FRAGMENT-LINEAR order; slots 1..3 = sentinel;
//      election control block reset (R9/R12-verified, verbatim) ----
__global__ void lstm_init(const float* __restrict__ hprev, u64* __restrict__ hg,
                          int* __restrict__ ectrl) {
  const int g = blockIdx.x * 256 + threadIdx.x;    // 0..16383
  if (blockIdx.x == 0 && threadIdx.x < 16)
    __hip_atomic_store(ectrl + threadIdx.x, (threadIdx.x == 8) ? -1 : 0,
                       __ATOMIC_RELAXED, __HIP_MEMORY_SCOPE_AGENT);
  const int slot = g >> 12, w = g & 4095;
  u64 v = SENTW;
  if (slot == 0) {
    const int f8 = w >> 1;
    const int b  = ((f8 >> 6) & 1) * 16 + (f8 & 15);
    const int c0 = (f8 >> 7) * 32 + ((f8 >> 4) & 3) * 8 + (w & 1) * 4;
    const float* s = hprev + (size_t)b * NH + c0;
    union { u64 u; f16 h[4]; } pk;
    pk.h[0] = (f16)s[0]; pk.h[1] = (f16)s[1]; pk.h[2] = (f16)s[2]; pk.h[3] = (f16)s[3];
    v = pk.u;
  }
  __hip_atomic_store(hg + g, v, __ATOMIC_RELAXED, __HIP_MEMORY_SCOPE_AGENT);
}

// ---- xproj: xp[t][col][b] = u64{4 gates f16} = Wih.x_t + bias (R7-R12 verified).
// ONLY change vs R12: cb = blockIdx.x (fast) so the 32 co-dispatched blocks per
// t-chunk share the same 1MB X window in L2/LLC (X HBM traffic ~4GB -> ~128MB).
// Index math is identical; xp content independent of dispatch order. ----
__global__ void __launch_bounds__(256, 1)
lstm_xproj(const float* __restrict__ X, const float* __restrict__ Wih,
           const float* __restrict__ bias, u64* __restrict__ xp) {
  __shared__ __align__(16) f16 x_lds[16384];
  const int tid = threadIdx.x, lane = tid & 63;
  const int wv = tid >> 6, l15 = lane & 15, lg = lane >> 4;
  const int cb = blockIdx.x, tb = blockIdx.y;
  const int colbase = cb * 16 + wv * 4;

  f16x8 wf[16];
#pragma unroll
  for (int kt = 0; kt < 16; ++kt) {
    const float* src = Wih + ((size_t)(l15 & 3) * NH + colbase + (l15 >> 2)) * ND + kt * 32 + lg * 8;
    f32x4 u0 = *(const f32x4*)src, u1 = *(const f32x4*)(src + 4);
    f16x8 w;
    w[0]=(f16)u0[0]; w[1]=(f16)u0[1]; w[2]=(f16)u0[2]; w[3]=(f16)u0[3];
    w[4]=(f16)u1[0]; w[5]=(f16)u1[1]; w[6]=(f16)u1[2]; w[7]=(f16)u1[3];
    wf[kt] = w;
  }
  const int mycol = colbase + lg;
  float bs[4];
#pragma unroll
  for (int q = 0; q < 4; ++q) bs[q] = bias[q * NH + mycol];

  const int gb = tid >> 3, gc0 = (tid & 7) * 64;

  for (int tt = 0; tt < 16; ++tt) {
    const int t = tb * 16 + tt;
    const float* xs = X + ((size_t)gb * NT + t) * ND + gc0;
#pragma unroll
    for (int i = 0; i < 8; ++i) {
      f32x4 v0 = *(const f32x4*)(xs + 8 * i);
      f32x4 v1 = *(const f32x4*)(xs + 8 * i + 4);
      f16x8 h8;
      h8[0]=(f16)v0[0]; h8[1]=(f16)v0[1]; h8[2]=(f16)v0[2]; h8[3]=(f16)v0[3];
      h8[4]=(f16)v1[0]; h8[5]=(f16)v1[1]; h8[6]=(f16)v1[2]; h8[7]=(f16)v1[3];
      *(f16x8*)&x_lds[frag_idx(gb, gc0 + 8 * i) * 8] = h8;
    }
    __syncthreads();

    f32x4 acc0 = {0,0,0,0}, acc1 = {0,0,0,0};
#pragma unroll
    for (int kt = 0; kt < 16; ++kt) {
      f16x8 b0 = *(const f16x8*)&x_lds[((kt * 2 + 0) * 64 + lane) * 8];
      f16x8 b1 = *(const f16x8*)&x_lds[((kt * 2 + 1) * 64 + lane) * 8];
      acc0 = __builtin_amdgcn_mfma_f32_16x16x32_f16(wf[kt], b0, acc0, 0, 0, 0);
      acc1 = __builtin_amdgcn_mfma_f32_16x16x32_f16(wf[kt], b1, acc1, 0, 0, 0);
    }
#pragma unroll
    for (int bh = 0; bh < 2; ++bh) {
      const f32x4& a = bh ? acc1 : acc0;
      union { u64 u; f16 h[4]; } pk;
      pk.h[0] = (f16)(a[0] + bs[0]); pk.h[1] = (f16)(a[1] + bs[1]);
      pk.h[2] = (f16)(a[2] + bs[2]); pk.h[3] = (f16)(a[3] + bs[3]);
      __hip_atomic_store(xp + ((size_t)t * NH + mycol) * 32 + bh * 16 + l15, pk.u,
                         __ATOMIC_RELAXED, __HIP_MEMORY_SCOPE_AGENT);
    }
    __syncthreads();
  }
}

// ---- persistent recurrent kernel: 256 launched, 16 elected (one XCD).
//      BYTE-IDENTICAL to R12 (last proven-good: 7.6ms rec, absmax 1.95e-3). ----
__global__ void __launch_bounds__(256, 1)
lstm_rec(const float* __restrict__ Whh,   // [4H][H] f32
         const u64*   __restrict__ xp,    // [T][512][32] u64 (4 gates f16)
         float* __restrict__ out,         // [32][512] f32
         u64*   __restrict__ hg,          // [4][4096] u64, FRAGMENT-LINEAR
         int*   __restrict__ ectrl) {     // [0..7] per-XCD counters, [8] winner
  __shared__ __align__(16) f16 hbuf[2][16384];
  __shared__ int s_wg;

  const int tid = threadIdx.x;

  // ---- election: first XCD to check in 16 WGs wins (R9-verified) ----
  u32 xcc;
  asm volatile("s_getreg_b32 %0, hwreg(HW_REG_XCC_ID)" : "=s"(xcc));
  xcc &= 7;
  if (tid == 0) {
    int r = __hip_atomic_fetch_add(ectrl + xcc, 1, __ATOMIC_RELAXED, __HIP_MEMORY_SCOPE_AGENT);
    if (r == NWG - 1) {
      int exp = -1;
      __hip_atomic_compare_exchange_strong(ectrl + 8, &exp, (int)xcc,
          __ATOMIC_RELAXED, __ATOMIC_RELAXED, __HIP_MEMORY_SCOPE_AGENT);
    }
    int w;
    do { w = __hip_atomic_load(ectrl + 8, __ATOMIC_RELAXED, __HIP_MEMORY_SCOPE_AGENT); } while (w < 0);
    s_wg = (w == (int)xcc && r < NWG) ? r : -1;
  }
  __syncthreads();
  if (s_wg < 0) return;
  const int wgid = s_wg;

  const int lane = tid & 63;
  const int wv = tid >> 6, l15 = lane & 15, lg = lane >> 4;
  const int colW = wgid * 32 + wv * 8;

  // resident Whh A-frags: 2 col-quads x 16 kt = 128 VGPRs
  f16x8 wfa[2][16];
#pragma unroll
  for (int a = 0; a < 2; ++a)
#pragma unroll
    for (int kt = 0; kt < 16; ++kt) {
      const float* src = Whh + ((size_t)(l15 & 3) * NH + colW + a * 4 + (l15 >> 2)) * NH + kt * 32 + lg * 8;
      f32x4 u0 = *(const f32x4*)src, u1 = *(const f32x4*)(src + 4);
      f16x8 w;
      w[0]=(f16)u0[0]; w[1]=(f16)u0[1]; w[2]=(f16)u0[2]; w[3]=(f16)u0[3];
      w[4]=(f16)u1[0]; w[5]=(f16)u1[1]; w[6]=(f16)u1[2]; w[7]=(f16)u1[3];
      wfa[a][kt] = w;
    }

  u16* hgh = (u16*)hg;
  int phw[2][2], qaddr[2][2], oaddr[2][2];
#pragma unroll
  for (int a = 0; a < 2; ++a)
#pragma unroll
    for (int bh = 0; bh < 2; ++bh) {
      const int b = bh * 16 + l15, col = colW + a * 4 + lg;
      phw[a][bh]   = ((wgid * 2 + bh) * 64 + wv * 16 + l15) * 8 + a * 4 + lg;
      qaddr[a][bh] = col * 32 + b;
      oaddr[a][bh] = b * NH + col;
    }

  float c[2][2] = {{0.f, 0.f}, {0.f, 0.f}};
  int mode = 0;   // 0 = sc0 XCD-local fast path; 1 = agent/LLC fallback (sticky)

  // prologue: xv = xp(0) (drained by the first gather's vmcnt(0))
  u64 xv[2][2];
#pragma unroll
  for (int a = 0; a < 2; ++a)
#pragma unroll
    for (int bh = 0; bh < 2; ++bh) xv[a][bh] = xp[qaddr[a][bh]];

  for (int t = 0; t < NT; ++t) {
    // (1) reset slot (t+2)&3 (acked by the gather's vmcnt(0) before any publish)
    {
      u16* rb = hgh + ((size_t)((t + 2) & 3) << 14);
#pragma unroll
      for (int a = 0; a < 2; ++a)
#pragma unroll
        for (int bh = 0; bh < 2; ++bh)
          st_u16_sc0(rb + phw[a][bh], SENTH);
    }

    // (2) spin-gather h(t) from slot t&3: FULL re-gather each round (proven live)
    u64 g[16];
    const u64* slot = hg + ((size_t)(t & 3) << 12);
    if (mode == 0) {
      int rounds = 0;
      for (;;) {
        gather16_sc0(slot, (u32)tid, g);
        u32 bad = 0;
#pragma unroll
        for (int i = 0; i < 16; ++i) if (has_sent(g[i])) bad |= 1u << i;
        if (!__any(bad != 0)) break;
        if (++rounds == 256) { mode = 1; break; }   // containment: degrade, don't hang
      }
    }
    if (mode) {
      const u64* src = slot + tid;
#pragma unroll
      for (int i = 0; i < 16; ++i)
        g[i] = __hip_atomic_load(src + 256 * i, __ATOMIC_RELAXED, __HIP_MEMORY_SCOPE_AGENT);
      for (;;) {
        u32 bad = 0;
#pragma unroll
        for (int i = 0; i < 16; ++i) if (has_sent(g[i])) bad |= 1u << i;
        if (!__any(bad != 0)) break;
#pragma unroll
        for (int i = 0; i < 16; ++i)
          if (bad & (1u << i))
            g[i] = __hip_atomic_load(src + 256 * i, __ATOMIC_RELAXED, __HIP_MEMORY_SCOPE_AGENT);
      }
      asm volatile("s_waitcnt vmcnt(0)" ::: "memory");
    }

    // (3) scatter to LDS = identity (hg fragment-linear), b64 writes
    {
      u64* hb64 = (u64*)hbuf[t & 1];
#pragma unroll
      for (int i = 0; i < 16; ++i)
        hb64[tid + 256 * i] = g[i];
    }
    __syncthreads();

    // (4) prefetch xp(t+1) — consumed NEXT step (>=1 step slack; next gather's
    //     vmcnt(0) guarantees arrival before use)
    const int tn = (t < NT - 1) ? t + 1 : NT - 1;
    const u64* xpn = xp + (size_t)tn * 16384;
    u64 xvn[2][2];
#pragma unroll
    for (int a = 0; a < 2; ++a)
#pragma unroll
      for (int bh = 0; bh < 2; ++bh) xvn[a][bh] = xpn[qaddr[a][bh]];

    // (5) MFMA over K=512 (linear conflict-free b128 reads)
    f32x4 acc[2][2] = {{{0,0,0,0},{0,0,0,0}},{{0,0,0,0},{0,0,0,0}}};
    {
      const f16* hb = hbuf[t & 1];
#pragma unroll
      for (int kt = 0; kt < 16; ++kt) {
        f16x8 b0 = *(const f16x8*)&hb[((kt * 2 + 0) * 64 + lane) * 8];
        f16x8 b1 = *(const f16x8*)&hb[((kt * 2 + 1) * 64 + lane) * 8];
        acc[0][0] = __builtin_amdgcn_mfma_f32_16x16x32_f16(wfa[0][kt], b0, acc[0][0], 0, 0, 0);
        acc[1][0] = __builtin_amdgcn_mfma_f32_16x16x32_f16(wfa[1][kt], b0, acc[1][0], 0, 0, 0);
        acc[0][1] = __builtin_amdgcn_mfma_f32_16x16x32_f16(wfa[0][kt], b1, acc[0][1], 0, 0, 0);
        acc[1][1] = __builtin_amdgcn_mfma_f32_16x16x32_f16(wfa[1][kt], b1, acc[1][1], 0, 0, 0);
      }
    }

    // (6) in-register cell with xv (prefetched LAST step); publish h(t+1) (sc0)
    {
      u16* pb = hgh + ((size_t)((t + 1) & 3) << 14);
#pragma unroll
      for (int a = 0; a < 2; ++a)
#pragma unroll
        for (int bh = 0; bh < 2; ++bh) {
          const f16* xg = (const f16*)&xv[a][bh];
          float gi = acc[a][bh][0] + (float)xg[0];
          float gf = acc[a][bh][1] + (float)xg[1];
          float gg = acc[a][bh][2] + (float)xg[2];
          float go = acc[a][bh][3] + (float)xg[3];
          c[a][bh] = sigf(gf) * c[a][bh] + sigf(gi) * tanhf_(gg);
          float hv = sigf(go) * tanhf_(c[a][bh]);
          union { f16 h; u16 u; } cv; cv.h = (f16)hv;
          st_u16_sc0(pb + phw[a][bh], cv.u);
          if (t == NT - 1) out[oaddr[a][bh]] = hv;
        }
    }

    // (7) roll xp prefetch
#pragma unroll
    for (int a = 0; a < 2; ++a)
#pragma unroll
      for (int bh = 0; bh < 2; ++bh) xv[a][bh] = xvn[a][bh];
  }
}

extern "C" void kernel_launch(void* const* d_in, const int* in_sizes, int n_in,
                              void* d_out, int out_size, void* d_ws, size_t ws_size,
                              hipStream_t stream) {
  const float* X     = (const float*)d_in[0];  // [32][2048][512]
  const float* hprev = (const float*)d_in[1];  // [32][512]
  const float* Wih   = (const float*)d_in[2];  // [2048][512]
  const float* Whh   = (const float*)d_in[3];  // [2048][512]
  const float* bias  = (const float*)d_in[4];  // [2048]
  float* out = (float*)d_out;

  u64* hg    = (u64*)d_ws;                                     // 128 KiB
  int* ectrl = (int*)((char*)d_ws + (size_t)(1 << 17));        // 64 B used
  u64* xp    = (u64*)((char*)d_ws + (size_t)(1 << 17) + 4096); // 256 MiB

  hipLaunchKernelGGL(lstm_init, dim3(64), dim3(256), 0, stream, hprev, hg, ectrl);
  hipLaunchKernelGGL(lstm_xproj, dim3(32, 128), dim3(256), 0, stream, X, Wih, bias, xp);
  hipLaunchKernelGGL(lstm_rec, dim3(256), dim3(256), 0, stream, Whh, xp, out, hg, ectrl);
}

// Round 17
// 8270.506 us; speedup vs baseline: 1.0408x; 1.0408x over previous
//
#include <hip/hip_runtime.h>

typedef _Float16 f16;
typedef _Float16 f16x8 __attribute__((ext_vector_type(8)));
typedef float f32x4 __attribute__((ext_vector_type(4)));
typedef unsigned long long u64;
typedef unsigned short u16;
typedef unsigned int u32;

#define NT 2048
#define ND 512
#define NH 512
#define NWG 16
#define SENTW 0xFFFFFFFFFFFFFFFFull
#define SENTH ((u16)0xFFFFu)

__device__ __forceinline__ float sigf(float x)  { return 1.0f / (1.0f + __expf(-x)); }
__device__ __forceinline__ float tanhf_(float x){ return 2.0f / (1.0f + __expf(-2.0f * x)) - 1.0f; }

// any halfword of x == 0xFFFF ? (h finite -> f16 pattern 0xFFFF (NaN) unreachable)
__device__ __forceinline__ bool has_sent(u64 x) {
  u64 a = x & (x >> 8); a &= (a >> 4); a &= (a >> 2); a &= (a >> 1);
  return (a & 0x0001000100010001ull) != 0ull;
}

__device__ __forceinline__ int frag_idx(int b, int k0) {
  return ((k0 >> 5) * 2 + (b >> 4)) * 64 + ((k0 & 31) >> 3) * 16 + (b & 15);
}

// XCD-local (L2-coherent) primitives: sc0 bypasses L1, served by the XCD's L2.
__device__ __forceinline__ void st_u16_sc0(u16* p, u32 v) {
  asm volatile("global_store_short %0, %1, off sc0" :: "v"(p), "v"(v) : "memory");
}

// FULL-slot sweep (R9/R12 proven-live): words tid + 256*i, one vmcnt(0).
// Liveness is a COLLECTIVE property: all waves sweep the full 32KB each round.
// Narrower variants (flags, selective words, quarters) starve — R10/R11/R15.
__device__ __forceinline__ void gather16_sc0(const u64* slot, u32 tid, u64* g) {
  const u32 voff = tid * 8u;
  asm volatile(
    "global_load_dwordx2 %0, %16, %17 sc0\n\t"
    "global_load_dwordx2 %1, %16, %17 offset:2048 sc0\n\t"
    "global_load_dwordx2 %2, %16, %18 sc0\n\t"
    "global_load_dwordx2 %3, %16, %18 offset:2048 sc0\n\t"
    "global_load_dwordx2 %4, %16, %19 sc0\n\t"
    "global_load_dwordx2 %5, %16, %19 offset:2048 sc0\n\t"
    "global_load_dwordx2 %6, %16, %20 sc0\n\t"
    "global_load_dwordx2 %7, %16, %20 offset:2048 sc0\n\t"
    "global_load_dwordx2 %8, %16, %21 sc0\n\t"
    "global_load_dwordx2 %9, %16, %21 offset:2048 sc0\n\t"
    "global_load_dwordx2 %10, %16, %22 sc0\n\t"
    "global_load_dwordx2 %11, %16, %22 offset:2048 sc0\n\t"
    "global_load_dwordx2 %12, %16, %23 sc0\n\t"
    "global_load_dwordx2 %13, %16, %23 offset:2048 sc0\n\t"
    "global_load_dwordx2 %14, %16, %24 sc0\n\t"
    "global_load_dwordx2 %15, %16, %24 offset:2048 sc0\n\t"
    "s_waitcnt vmcnt(0)"
    : "=&v"(g[0]), "=&v"(g[1]), "=&v"(g[2]), "=&v"(g[3]),
      "=&v"(g[4]), "=&v"(g[5]), "=&v"(g[6]), "=&v"(g[7]),
      "=&v"(g[8]), "=&v"(g[9]), "=&v"(g[10]), "=&v"(g[11]),
      "=&v"(g[12]), "=&v"(g[13]), "=&v"(g[14]), "=&v"(g[15])
    : "v"(voff),
      "s"(slot), "s"(slot + 512), "s"(slot + 1024), "s"(slot + 1536),
      "s"(slot + 2048), "s"(slot + 2560), "s"(slot + 3072), "s"(slot + 3584)
    : "memory");
}

// ---- init: hg slot0 = h_prev in FRAGMENT-LINEAR order; slots 1..3 = sentinel;
//      election control block reset (R9/R12-verified, verbatim) ----
__global__ void lstm_init(const float* __restrict__ hprev, u64* __restrict__ hg,
                          int* __restrict__ ectrl) {
  const int g = blockIdx.x * 256 + threadIdx.x;    // 0..16383
  if (blockIdx.x == 0 && threadIdx.x < 16)
    __hip_atomic_store(ectrl + threadIdx.x, (threadIdx.x == 8) ? -1 : 0,
                       __ATOMIC_RELAXED, __HIP_MEMORY_SCOPE_AGENT);
  const int slot = g >> 12, w = g & 4095;
  u64 v = SENTW;
  if (slot == 0) {
    const int f8 = w >> 1;
    const int b  = ((f8 >> 6) & 1) * 16 + (f8 & 15);
    const int c0 = (f8 >> 7) * 32 + ((f8 >> 4) & 3) * 8 + (w & 1) * 4;
    const float* s = hprev + (size_t)b * NH + c0;
    union { u64 u; f16 h[4]; } pk;
    pk.h[0] = (f16)s[0]; pk.h[1] = (f16)s[1]; pk.h[2] = (f16)s[2]; pk.h[3] = (f16)s[3];
    v = pk.u;
  }
  __hip_atomic_store(hg + g, v, __ATOMIC_RELAXED, __HIP_MEMORY_SCOPE_AGENT);
}

// ---- xproj: xp[t][col][b] = u64{4 gates f16} = Wih.x_t + bias.
// R17 change (internal only, plain intra-WG GEMM): double-buffered LDS staging,
// ONE barrier per timestep, t+1 global loads issued before t's MFMAs so HBM
// latency hides under compute. Index math identical to the verified version. ----
__global__ void __launch_bounds__(256, 1)
lstm_xproj(const float* __restrict__ X, const float* __restrict__ Wih,
           const float* __restrict__ bias, u64* __restrict__ xp) {
  __shared__ __align__(16) f16 x_lds[2][16384];
  const int tid = threadIdx.x, lane = tid & 63;
  const int wv = tid >> 6, l15 = lane & 15, lg = lane >> 4;
  const int cb = blockIdx.x, tb = blockIdx.y;
  const int colbase = cb * 16 + wv * 4;

  f16x8 wf[16];
#pragma unroll
  for (int kt = 0; kt < 16; ++kt) {
    const float* src = Wih + ((size_t)(l15 & 3) * NH + colbase + (l15 >> 2)) * ND + kt * 32 + lg * 8;
    f32x4 u0 = *(const f32x4*)src, u1 = *(const f32x4*)(src + 4);
    f16x8 w;
    w[0]=(f16)u0[0]; w[1]=(f16)u0[1]; w[2]=(f16)u0[2]; w[3]=(f16)u0[3];
    w[4]=(f16)u1[0]; w[5]=(f16)u1[1]; w[6]=(f16)u1[2]; w[7]=(f16)u1[3];
    wf[kt] = w;
  }
  const int mycol = colbase + lg;
  float bs[4];
#pragma unroll
  for (int q = 0; q < 4; ++q) bs[q] = bias[q * NH + mycol];

  const int gb = tid >> 3, gc0 = (tid & 7) * 64;

  // prologue: stage t = tb*16 into x_lds[0]
  {
    const float* xs = X + ((size_t)gb * NT + tb * 16) * ND + gc0;
#pragma unroll
    for (int i = 0; i < 8; ++i) {
      f32x4 v0 = *(const f32x4*)(xs + 8 * i);
      f32x4 v1 = *(const f32x4*)(xs + 8 * i + 4);
      f16x8 h8;
      h8[0]=(f16)v0[0]; h8[1]=(f16)v0[1]; h8[2]=(f16)v0[2]; h8[3]=(f16)v0[3];
      h8[4]=(f16)v1[0]; h8[5]=(f16)v1[1]; h8[6]=(f16)v1[2]; h8[7]=(f16)v1[3];
      *(f16x8*)&x_lds[0][frag_idx(gb, gc0 + 8 * i) * 8] = h8;
    }
  }
  __syncthreads();

  for (int tt = 0; tt < 16; ++tt) {
    const int t = tb * 16 + tt;

    // (1) issue t+1's global loads into regs (latency hides under MFMAs)
    f32x4 pv[16];
    if (tt < 15) {
      const float* xs = X + ((size_t)gb * NT + t + 1) * ND + gc0;
#pragma unroll
      for (int i = 0; i < 16; ++i) pv[i] = *(const f32x4*)(xs + 4 * i);
    }

    // (2) MFMA on x_lds[tt&1] (verified pattern)
    f32x4 acc0 = {0,0,0,0}, acc1 = {0,0,0,0};
    {
      const f16* xb = x_lds[tt & 1];
#pragma unroll
      for (int kt = 0; kt < 16; ++kt) {
        f16x8 b0 = *(const f16x8*)&xb[((kt * 2 + 0) * 64 + lane) * 8];
        f16x8 b1 = *(const f16x8*)&xb[((kt * 2 + 1) * 64 + lane) * 8];
        acc0 = __builtin_amdgcn_mfma_f32_16x16x32_f16(wf[kt], b0, acc0, 0, 0, 0);
        acc1 = __builtin_amdgcn_mfma_f32_16x16x32_f16(wf[kt], b1, acc1, 0, 0, 0);
      }
    }

    // (3) store xp(t) (verified pattern)
#pragma unroll
    for (int bh = 0; bh < 2; ++bh) {
      const f32x4& a = bh ? acc1 : acc0;
      union { u64 u; f16 h[4]; } pk;
      pk.h[0] = (f16)(a[0] + bs[0]); pk.h[1] = (f16)(a[1] + bs[1]);
      pk.h[2] = (f16)(a[2] + bs[2]); pk.h[3] = (f16)(a[3] + bs[3]);
      __hip_atomic_store(xp + ((size_t)t * NH + mycol) * 32 + bh * 16 + l15, pk.u,
                         __ATOMIC_RELAXED, __HIP_MEMORY_SCOPE_AGENT);
    }

    // (4) write prefetched t+1 into the OTHER buffer (no conflict with (2):
    //     different buffer; cross-iteration hazards covered by the one barrier)
    if (tt < 15) {
#pragma unroll
      for (int i = 0; i < 8; ++i) {
        f32x4 v0 = pv[2 * i], v1 = pv[2 * i + 1];
        f16x8 h8;
        h8[0]=(f16)v0[0]; h8[1]=(f16)v0[1]; h8[2]=(f16)v0[2]; h8[3]=(f16)v0[3];
        h8[4]=(f16)v1[0]; h8[5]=(f16)v1[1]; h8[6]=(f16)v1[2]; h8[7]=(f16)v1[3];
        *(f16x8*)&x_lds[(tt + 1) & 1][frag_idx(gb, gc0 + 8 * i) * 8] = h8;
      }
    }
    __syncthreads();
  }
}

// ---- persistent recurrent kernel: 256 launched, 16 elected (one XCD).
//      BYTE-IDENTICAL to R12/R16 (proven-good 3x: ~7.55ms rec, absmax 1.95e-3). ----
__global__ void __launch_bounds__(256, 1)
lstm_rec(const float* __restrict__ Whh,   // [4H][H] f32
         const u64*   __restrict__ xp,    // [T][512][32] u64 (4 gates f16)
         float* __restrict__ out,         // [32][512] f32
         u64*   __restrict__ hg,          // [4][4096] u64, FRAGMENT-LINEAR
         int*   __restrict__ ectrl) {     // [0..7] per-XCD counters, [8] winner
  __shared__ __align__(16) f16 hbuf[2][16384];
  __shared__ int s_wg;

  const int tid = threadIdx.x;

  // ---- election: first XCD to check in 16 WGs wins (R9-verified) ----
  u32 xcc;
  asm volatile("s_getreg_b32 %0, hwreg(HW_REG_XCC_ID)" : "=s"(xcc));
  xcc &= 7;
  if (tid == 0) {
    int r = __hip_atomic_fetch_add(ectrl + xcc, 1, __ATOMIC_RELAXED, __HIP_MEMORY_SCOPE_AGENT);
    if (r == NWG - 1) {
      int exp = -1;
      __hip_atomic_compare_exchange_strong(ectrl + 8, &exp, (int)xcc,
          __ATOMIC_RELAXED, __ATOMIC_RELAXED, __HIP_MEMORY_SCOPE_AGENT);
    }
    int w;
    do { w = __hip_atomic_load(ectrl + 8, __ATOMIC_RELAXED, __HIP_MEMORY_SCOPE_AGENT); } while (w < 0);
    s_wg = (w == (int)xcc && r < NWG) ? r : -1;
  }
  __syncthreads();
  if (s_wg < 0) return;
  const int wgid = s_wg;

  const int lane = tid & 63;
  const int wv = tid >> 6, l15 = lane & 15, lg = lane >> 4;
  const int colW = wgid * 32 + wv * 8;

  // resident Whh A-frags: 2 col-quads x 16 kt = 128 VGPRs
  f16x8 wfa[2][16];
#pragma unroll
  for (int a = 0; a < 2; ++a)
#pragma unroll
    for (int kt = 0; kt < 16; ++kt) {
      const float* src = Whh + ((size_t)(l15 & 3) * NH + colW + a * 4 + (l15 >> 2)) * NH + kt * 32 + lg * 8;
      f32x4 u0 = *(const f32x4*)src, u1 = *(const f32x4*)(src + 4);
      f16x8 w;
      w[0]=(f16)u0[0]; w[1]=(f16)u0[1]; w[2]=(f16)u0[2]; w[3]=(f16)u0[3];
      w[4]=(f16)u1[0]; w[5]=(f16)u1[1]; w[6]=(f16)u1[2]; w[7]=(f16)u1[3];
      wfa[a][kt] = w;
    }

  u16* hgh = (u16*)hg;
  int phw[2][2], qaddr[2][2], oaddr[2][2];
#pragma unroll
  for (int a = 0; a < 2; ++a)
#pragma unroll
    for (int bh = 0; bh < 2; ++bh) {
      const int b = bh * 16 + l15, col = colW + a * 4 + lg;
      phw[a][bh]   = ((wgid * 2 + bh) * 64 + wv * 16 + l15) * 8 + a * 4 + lg;
      qaddr[a][bh] = col * 32 + b;
      oaddr[a][bh] = b * NH + col;
    }

  float c[2][2] = {{0.f, 0.f}, {0.f, 0.f}};
  int mode = 0;   // 0 = sc0 XCD-local fast path; 1 = agent/LLC fallback (sticky)

  // prologue: xv = xp(0) (drained by the first gather's vmcnt(0))
  u64 xv[2][2];
#pragma unroll
  for (int a = 0; a < 2; ++a)
#pragma unroll
    for (int bh = 0; bh < 2; ++bh) xv[a][bh] = xp[qaddr[a][bh]];

  for (int t = 0; t < NT; ++t) {
    // (1) reset slot (t+2)&3 (acked by the gather's vmcnt(0) before any publish)
    {
      u16* rb = hgh + ((size_t)((t + 2) & 3) << 14);
#pragma unroll
      for (int a = 0; a < 2; ++a)
#pragma unroll
        for (int bh = 0; bh < 2; ++bh)
          st_u16_sc0(rb + phw[a][bh], SENTH);
    }

    // (2) spin-gather h(t) from slot t&3: FULL re-gather each round (proven live)
    u64 g[16];
    const u64* slot = hg + ((size_t)(t & 3) << 12);
    if (mode == 0) {
      int rounds = 0;
      for (;;) {
        gather16_sc0(slot, (u32)tid, g);
        u32 bad = 0;
#pragma unroll
        for (int i = 0; i < 16; ++i) if (has_sent(g[i])) bad |= 1u << i;
        if (!__any(bad != 0)) break;
        if (++rounds == 256) { mode = 1; break; }   // containment: degrade, don't hang
      }
    }
    if (mode) {
      const u64* src = slot + tid;
#pragma unroll
      for (int i = 0; i < 16; ++i)
        g[i] = __hip_atomic_load(src + 256 * i, __ATOMIC_RELAXED, __HIP_MEMORY_SCOPE_AGENT);
      for (;;) {
        u32 bad = 0;
#pragma unroll
        for (int i = 0; i < 16; ++i) if (has_sent(g[i])) bad |= 1u << i;
        if (!__any(bad != 0)) break;
#pragma unroll
        for (int i = 0; i < 16; ++i)
          if (bad & (1u << i))
            g[i] = __hip_atomic_load(src + 256 * i, __ATOMIC_RELAXED, __HIP_MEMORY_SCOPE_AGENT);
      }
      asm volatile("s_waitcnt vmcnt(0)" ::: "memory");
    }

    // (3) scatter to LDS = identity (hg fragment-linear), b64 writes
    {
      u64* hb64 = (u64*)hbuf[t & 1];
#pragma unroll
      for (int i = 0; i < 16; ++i)
        hb64[tid + 256 * i] = g[i];
    }
    __syncthreads();

    // (4) prefetch xp(t+1) — consumed NEXT step (>=1 step slack; next gather's
    //     vmcnt(0) guarantees arrival before use)
    const int tn = (t < NT - 1) ? t + 1 : NT - 1;
    const u64* xpn = xp + (size_t)tn * 16384;
    u64 xvn[2][2];
#pragma unroll
    for (int a = 0; a < 2; ++a)
#pragma unroll
      for (int bh = 0; bh < 2; ++bh) xvn[a][bh] = xpn[qaddr[a][bh]];

    // (5) MFMA over K=512 (linear conflict-free b128 reads)
    f32x4 acc[2][2] = {{{0,0,0,0},{0,0,0,0}},{{0,0,0,0},{0,0,0,0}}};
    {
      const f16* hb = hbuf[t & 1];
#pragma unroll
      for (int kt = 0; kt < 16; ++kt) {
        f16x8 b0 = *(const f16x8*)&hb[((kt * 2 + 0) * 64 + lane) * 8];
        f16x8 b1 = *(const f16x8*)&hb[((kt * 2 + 1) * 64 + lane) * 8];
        acc[0][0] = __builtin_amdgcn_mfma_f32_16x16x32_f16(wfa[0][kt], b0, acc[0][0], 0, 0, 0);
        acc[1][0] = __builtin_amdgcn_mfma_f32_16x16x32_f16(wfa[1][kt], b0, acc[1][0], 0, 0, 0);
        acc[0][1] = __builtin_amdgcn_mfma_f32_16x16x32_f16(wfa[0][kt], b1, acc[0][1], 0, 0, 0);
        acc[1][1] = __builtin_amdgcn_mfma_f32_16x16x32_f16(wfa[1][kt], b1, acc[1][1], 0, 0, 0);
      }
    }

    // (6) in-register cell with xv (prefetched LAST step); publish h(t+1) (sc0)
    {
      u16* pb = hgh + ((size_t)((t + 1) & 3) << 14);
#pragma unroll
      for (int a = 0; a < 2; ++a)
#pragma unroll
        for (int bh = 0; bh < 2; ++bh) {
          const f16* xg = (const f16*)&xv[a][bh];
          float gi = acc[a][bh][0] + (float)xg[0];
          float gf = acc[a][bh][1] + (float)xg[1];
          float gg = acc[a][bh][2] + (float)xg[2];
          float go = acc[a][bh][3] + (float)xg[3];
          c[a][bh] = sigf(gf) * c[a][bh] + sigf(gi) * tanhf_(gg);
          float hv = sigf(go) * tanhf_(c[a][bh]);
          union { f16 h; u16 u; } cv; cv.h = (f16)hv;
          st_u16_sc0(pb + phw[a][bh], cv.u);
          if (t == NT - 1) out[oaddr[a][bh]] = hv;
        }
    }

    // (7) roll xp prefetch
#pragma unroll
    for (int a = 0; a < 2; ++a)
#pragma unroll
      for (int bh = 0; bh < 2; ++bh) xv[a][bh] = xvn[a][bh];
  }
}

extern "C" void kernel_launch(void* const* d_in, const int* in_sizes, int n_in,
                              void* d_out, int out_size, void* d_ws, size_t ws_size,
                              hipStream_t stream) {
  const float* X     = (const float*)d_in[0];  // [32][2048][512]
  const float* hprev = (const float*)d_in[1];  // [32][512]
  const float* Wih   = (const float*)d_in[2];  // [2048][512]
  const float* Whh   = (const float*)d_in[3];  // [2048][512]
  const float* bias  = (const float*)d_in[4];  // [2048]
  float* out = (float*)d_out;

  u64* hg    = (u64*)d_ws;                                     // 128 KiB
  int* ectrl = (int*)((char*)d_ws + (size_t)(1 << 17));        // 64 B used
  u64* xp    = (u64*)((char*)d_ws + (size_t)(1 << 17) + 4096); // 256 MiB

  hipLaunchKernelGGL(lstm_init, dim3(64), dim3(256), 0, stream, hprev, hg, ectrl);
  hipLaunchKernelGGL(lstm_xproj, dim3(32, 128), dim3(256), 0, stream, X, Wih, bias, xp);
  hipLaunchKernelGGL(lstm_rec, dim3(256), dim3(256), 0, stream, Whh, xp, out, hg, ectrl);
}